// Round 11
// baseline (3670.623 us; speedup 1.0000x reference)
//
#include <hip/hip_runtime.h>
#include <stdint.h>

#define BB 32
#define LL 1024
#define NW 512
#define HH 768
#define HID 384
#define G4 1536   // 4*HID
#define EE 4
#define DLL 128
#define GIN 896   // H+DL
#define CWG 12    // column-group WGs (each handles BOTH dirs, 32 cols)
#define WGC 32    // h-cols per WG
#define HPAD 392  // padded LDS row stride (shorts)
#define HSLOT (16 * HID)   // one tagged h slot (u32 count)

typedef __attribute__((ext_vector_type(8))) short short8;
typedef __attribute__((ext_vector_type(4))) float f32x4;
typedef __attribute__((ext_vector_type(4))) unsigned int u32x4;
typedef __attribute__((ext_vector_type(2))) unsigned int u32x2;

__device__ __forceinline__ float bf2f(short s){
  union { unsigned int u; float f; } v; v.u = ((unsigned int)(unsigned short)s) << 16; return v.f;
}
__device__ __forceinline__ short f2bf(float f){
  union { float f; unsigned int u; } v; v.f = f;
  unsigned int r = v.u + 0x7fffu + ((v.u >> 16) & 1u);
  return (short)(r >> 16);
}
__device__ __forceinline__ float sigm(float x){ return 1.f / (1.f + __expf(-x)); }
__device__ __forceinline__ float ftanh(float x){ float e = __expf(2.f * x); return 1.f - 2.f / (e + 1.f); }

__device__ __forceinline__ void gload16(const void* g, void* l){
  __builtin_amdgcn_global_load_lds(
      (const __attribute__((address_space(1))) unsigned int*)g,
      (__attribute__((address_space(3))) unsigned int*)l, 16, 0, 0);
}

// ---------------- f32 -> bf16 convert ----------------
__global__ void k_f2bf(const float* in, short* out, int n){
  int i = blockIdx.x * blockDim.x + threadIdx.x;
  int st = gridDim.x * blockDim.x;
  for (; i < n; i += st) out[i] = f2bf(in[i]);
}

// ---------------- segment mean pooling ----------------
__global__ __launch_bounds__(256) void k_segmean(const float* __restrict__ tok,
                                                 const int* __restrict__ wmap,
                                                 short* __restrict__ we_bf){
  int blk = blockIdx.x;
  int b = blk >> 9;
  int w = blk & 511;
  const int* m = wmap + b * LL;
  int lo = 0, hi = LL;
  while (lo < hi){ int mid = (lo + hi) >> 1; if (m[mid] < w) lo = mid + 1; else hi = mid; }
  int s = lo;
  int lo2 = s, hi2 = LL;
  while (lo2 < hi2){ int mid = (lo2 + hi2) >> 1; if (m[mid] <= w) lo2 = mid + 1; else hi2 = mid; }
  int e = lo2;
  float cnt = (float)(e - s);
  float denom = fmaxf(cnt, 1.f);
  for (int j = threadIdx.x; j < HH; j += 256){
    float acc = 0.f;
    for (int r = s; r < e; ++r) acc += tok[((size_t)b * LL + r) * HH + j];
    we_bf[((size_t)b * NW + w) * HH + j] = f2bf(acc / denom);
  }
}

// ---------------- GEMM: C[M,N] = A[M,K](bf16) * W[N,K]^T(bf16) + b1[n] + b2[n] ----------------
__global__ __launch_bounds__(256) void k_gemm_bt(const short* __restrict__ Abf,
                                                 const short* __restrict__ Wbf,
                                                 const float* __restrict__ b1,
                                                 const float* __restrict__ b2,
                                                 float* __restrict__ Cf,
                                                 int M, int N, int K){
  __shared__ __attribute__((aligned(16))) short As[128 * 32];
  __shared__ __attribute__((aligned(16))) short Bs[128 * 32];
  int ntiles = N >> 7;
  int m0 = (blockIdx.x / ntiles) << 7;
  int n0 = (blockIdx.x % ntiles) << 7;
  int tid = threadIdx.x, lane = tid & 63, wv = tid >> 6;
  int wm = (wv >> 1) << 6, wn = (wv & 1) << 6;
  f32x4 acc[4][4] = {};
  for (int kk = 0; kk < K; kk += 32){
#pragma unroll
    for (int q = 0; q < 2; ++q){
      int e = q * 256 + tid;
      int row = e >> 2, col = (e & 3) << 3;
      gload16(Abf + (size_t)(m0 + row) * K + kk + col, As + e * 8);
      gload16(Wbf + (size_t)(n0 + row) * K + kk + col, Bs + e * 8);
    }
    __syncthreads();
    short8 af[4], bfr[4];
#pragma unroll
    for (int x = 0; x < 4; ++x){
      af[x]  = *(const short8*)(As + (wm + x * 16 + (lane & 15)) * 32 + ((lane >> 4) << 3));
      bfr[x] = *(const short8*)(Bs + (wn + x * 16 + (lane & 15)) * 32 + ((lane >> 4) << 3));
    }
#pragma unroll
    for (int x = 0; x < 4; ++x)
#pragma unroll
      for (int y = 0; y < 4; ++y)
        acc[x][y] = __builtin_amdgcn_mfma_f32_16x16x32_bf16(af[x], bfr[y], acc[x][y], 0, 0, 0);
    __syncthreads();
  }
#pragma unroll
  for (int x = 0; x < 4; ++x)
#pragma unroll
    for (int y = 0; y < 4; ++y)
#pragma unroll
      for (int i = 0; i < 4; ++i){
        int mm = m0 + wm + x * 16 + ((lane >> 4) << 2) + i;
        int nn = n0 + wn + y * 16 + (lane & 15);
        Cf[(size_t)mm * N + nn] = acc[x][y][i] + b1[nn] + b2[nn];
      }
}

// ================= BiLSTM: 4-chain rotation (dir x batch-half), tags, counted vmcnt =================
// 12 WGs x 512 threads; each WG owns 32 cols of BOTH directions and cycles 4 independent chains:
// Y0=(d0,X0) Y1=(d1,X0) Y2=(d0,X1) Y3=(d1,X1). h(C,t): u32=(bf16<<16)|(t+1) in hbuf[C][t&1].
// Schedule per tick: head vmcnt(15) [steady] -> tag-check (retry=rare) -> strip->LDS -> barrier ->
// MFMA -> pre -> mid{h-load for tick+2, xg for tick+3} -> barrier -> cell -> {tagged store, hcat store}.
// Store->load-issue = 1.5 ticks (covers MALL propagation); load flight = 1.5 ticks (covers RT).
// Safety: all-column tag validation at each head is the back-pressure (a producer cannot overwrite
// slot s before every WG validated the previous tag in s). Tags make any vmcnt slack self-healing.

#define TB(dv, EXP) (((dv[0] ^ (EXP)) | (dv[1] ^ (EXP)) | (dv[2] ^ (EXP)) | (dv[3] ^ (EXP))) & 0xffffu)

#define HLOAD3(D0, D1, D2, PTR) do{ const unsigned int* _hp = (PTR); \
  asm volatile("global_load_dwordx4 %0, %1, off sc0 sc1" : "=v"(D0) : "v"(_hp + 0) : "memory"); \
  asm volatile("global_load_dwordx4 %0, %1, off sc0 sc1" : "=v"(D1) : "v"(_hp + 4) : "memory"); \
  asm volatile("global_load_dwordx4 %0, %1, off sc0 sc1" : "=v"(D2) : "v"(_hp + 8) : "memory"); }while(0)

#define RETRY3(D0, D1, D2, PTR, EXP) for(;;){ \
  unsigned int _bad = TB(D0, EXP) | TB(D1, EXP) | TB(D2, EXP); \
  if (__all(_bad == 0)) break; \
  __builtin_amdgcn_s_sleep(1); \
  HLOAD3(D0, D1, D2, PTR); \
  asm volatile("s_waitcnt vmcnt(0)" ::: "memory"); \
  __builtin_amdgcn_sched_barrier(0); }

#define STRIP3(D0, D1, D2) do{ \
  unsigned int _p0 = (D0[0] >> 16) | (D0[1] & 0xffff0000u); \
  unsigned int _p1 = (D0[2] >> 16) | (D0[3] & 0xffff0000u); \
  unsigned int _p2 = (D1[0] >> 16) | (D1[1] & 0xffff0000u); \
  unsigned int _p3 = (D1[2] >> 16) | (D1[3] & 0xffff0000u); \
  unsigned int _p4 = (D2[0] >> 16) | (D2[1] & 0xffff0000u); \
  unsigned int _p5 = (D2[2] >> 16) | (D2[3] & 0xffff0000u); \
  u32x2 _w0 = {_p0, _p1}, _w1 = {_p2, _p3}, _w2 = {_p4, _p5}; \
  short* _dst = &hs[eb * HPAD + scc]; \
  *(u32x2*)(_dst)     = _w0; \
  *(u32x2*)(_dst + 4) = _w1; \
  *(u32x2*)(_dst + 8) = _w2; }while(0)

#define XG_ISSUE(A0, A1, A2, A3, BASE, XHV, TACT) do{ \
  const float* _xp = (BASE) + ((size_t)((XHV) * 16 + q * 4) * NW + (TACT)) * G4 + colOff; \
  asm volatile("global_load_dword %0, %1, off" : "=v"(A0) : "v"(_xp) : "memory"); \
  asm volatile("global_load_dword %0, %1, off" : "=v"(A1) : "v"(_xp + (size_t)NW * G4) : "memory"); \
  asm volatile("global_load_dword %0, %1, off" : "=v"(A2) : "v"(_xp + (size_t)2 * NW * G4) : "memory"); \
  asm volatile("global_load_dword %0, %1, off" : "=v"(A3) : "v"(_xp + (size_t)3 * NW * G4) : "memory"); }while(0)

#define BARRIER_LGKM \
  asm volatile("s_waitcnt lgkmcnt(0)" ::: "memory"); \
  __builtin_amdgcn_s_barrier(); \
  __builtin_amdgcn_sched_barrier(0);

#define MFMA12(BF) { const short* _hr = &hs[fr * HPAD + q * 8]; \
  _Pragma("unroll") \
  for (int ks = 0; ks < 6; ++ks) \
    acc  = __builtin_amdgcn_mfma_f32_16x16x32_bf16(*(const short8*)(_hr + ks * 32), BF[ks], acc, 0, 0, 0); \
  _Pragma("unroll") \
  for (int ks = 6; ks < 12; ++ks) \
    acc2 = __builtin_amdgcn_mfma_f32_16x16x32_bf16(*(const short8*)(_hr + ks * 32), BF[ks], acc2, 0, 0, 0); \
  acc += acc2; }

#define PREW(A0, A1, A2, A3) \
  pre[g][q*4+0][nh*16+fr] = acc[0] + (A0); \
  pre[g][q*4+1][nh*16+fr] = acc[1] + (A1); \
  pre[g][q*4+2][nh*16+fr] = acc[2] + (A2); \
  pre[g][q*4+3][nh*16+fr] = acc[3] + (A3);

#define EW_STORE(CST, HBC, TACT, ROWBASE, HCOFF) do{ \
  float _gi = pre[0][eb][ecol], _gf = pre[1][eb][ecol]; \
  float _gg = pre[2][eb][ecol], _go = pre[3][eb][ecol]; \
  CST = sigm(_gf) * CST + sigm(_gi) * ftanh(_gg); \
  float _h = sigm(_go) * ftanh(CST); \
  unsigned int _hv = (unsigned int)(unsigned short)f2bf(_h); \
  unsigned int _wt = (_hv << 16) | ((unsigned int)(j + 1) & 0xffffu); \
  unsigned int* _hw = (HBC) + (size_t)(j & 1) * HSLOT + stoff; \
  asm volatile("global_store_dword %0, %1, off sc0 sc1" :: "v"(_hw), "v"(_wt) : "memory"); \
  short* _hc = hcat + ((size_t)((ROWBASE) + eb) * NW + (TACT)) * HH + (HCOFF); \
  asm volatile("global_store_short %0, %1, off" :: "v"(_hc), "v"(_hv) : "memory"); }while(0)

__global__ __launch_bounds__(512) void k_lstm(const float* __restrict__ xg_f,
                                              const float* __restrict__ xg_b,
                                              const short* __restrict__ whh_f,
                                              const short* __restrict__ whh_b,
                                              unsigned int* __restrict__ hbuf,
                                              short* __restrict__ hcat){
  int cg = blockIdx.x;
  int tid = threadIdx.x, lane = tid & 63, wv = tid >> 6;
  int q = lane >> 4, fr = lane & 15;
  int g = wv >> 1, nh = wv & 1;
  int jbase = g * HID + cg * WGC + nh * 16;
  int colOff = jbase + fr;

  // resident Whh fragments for BOTH directions: 2 x 48 VGPRs
  short8 bfragF[12], bfragB[12];
  {
    const short* wrF = whh_f + (size_t)(jbase + fr) * HID + q * 8;
    const short* wrB = whh_b + (size_t)(jbase + fr) * HID + q * 8;
#pragma unroll
    for (int ks = 0; ks < 12; ++ks)
      asm volatile("global_load_dwordx4 %0, %1, off" : "=v"(bfragF[ks]) : "v"(wrF + ks * 32) : "memory");
#pragma unroll
    for (int ks = 0; ks < 12; ++ks)
      asm volatile("global_load_dwordx4 %0, %1, off" : "=v"(bfragB[ks]) : "v"(wrB + ks * 32) : "memory");
    asm volatile("s_waitcnt vmcnt(0)" ::: "memory");
    __builtin_amdgcn_sched_barrier(0);
  }

  __shared__ __attribute__((aligned(16))) short hs[16 * HPAD];
  __shared__ float pre[4][16][34];

  int eb = tid >> 5, ecol = tid & 31;
  int scc = ecol * 12;                       // staging: 12 consecutive cells
  int ldoff = eb * HID + scc;
  int stoff = eb * HID + cg * WGC + ecol;
  int hcOff0 = cg * WGC + ecol;              // dir0 hcat col
  int hcOff1 = HID + cg * WGC + ecol;        // dir1 hcat col
  unsigned int* hb0 = hbuf;                  // chain (d0,X0)
  unsigned int* hb1 = hbuf + 2 * HSLOT;      // (d1,X0)
  unsigned int* hb2 = hbuf + 4 * HSLOT;      // (d0,X1)
  unsigned int* hb3 = hbuf + 6 * HSLOT;      // (d1,X1)

  float c0 = 0.f, c1 = 0.f, c2 = 0.f, c3 = 0.f;
  float x00, x01, x02, x03, x10, x11, x12, x13;
  float x20, x21, x22, x23, x30, x31, x32, x33;
  u32x4 dE0 = {}, dE1 = {}, dE2 = {}, dO0 = {}, dO1 = {}, dO2 = {};

  // prologue xg: ticks 0,1,2 (chains 0,1,2 at t=0)
  XG_ISSUE(x00, x01, x02, x03, xg_f, 0, 0);
  XG_ISSUE(x10, x11, x12, x13, xg_b, 0, NW - 1);
  XG_ISSUE(x20, x21, x22, x23, xg_f, 1, 0);

  for (int j = 0; j < NW; ++j){
    int ta0 = j;               // dir0 time index
    int ta1 = NW - 1 - j;      // dir1 time index
    int ps = (j - 1) & 1;      // slot holding h(.., j-1)
    unsigned int expect = (unsigned int)j & 0xffffu;

    //========== tick Y0: (d0, X0) ==========
    if (j == 0)            { asm volatile("s_waitcnt vmcnt(8)"  ::: "memory"); }
    else if (j == NW - 1)  { asm volatile("s_waitcnt vmcnt(0)"  ::: "memory"); }
    else                   { asm volatile("s_waitcnt vmcnt(15)" ::: "memory"); }
    __builtin_amdgcn_sched_barrier(0);
    if (j > 0){
      const unsigned int* hpr = hb0 + (size_t)ps * HSLOT + ldoff;
      RETRY3(dE0, dE1, dE2, hpr, expect);
      STRIP3(dE0, dE1, dE2);
    }
    BARRIER_LGKM;
    {
      f32x4 acc = {}, acc2 = {};
      if (j > 0) MFMA12(bfragF);
      PREW(x00, x01, x02, x03);
    }
    __builtin_amdgcn_sched_barrier(0);
    if (j >= 1) HLOAD3(dE0, dE1, dE2, hb2 + (size_t)ps * HSLOT + ldoff);      // h(ch2, j-1) for tick+2
    XG_ISSUE(x30, x31, x32, x33, xg_b, 1, ta1);                                // ch3 xg, tn=j
    BARRIER_LGKM;
    EW_STORE(c0, hb0, ta0, 0, hcOff0);

    //========== tick Y1: (d1, X0) ==========
    if (j == 0)            { asm volatile("s_waitcnt vmcnt(10)" ::: "memory"); }
    else if (j == NW - 1)  { asm volatile("s_waitcnt vmcnt(0)"  ::: "memory"); }
    else                   { asm volatile("s_waitcnt vmcnt(15)" ::: "memory"); }
    __builtin_amdgcn_sched_barrier(0);
    if (j > 0){
      const unsigned int* hpr = hb1 + (size_t)ps * HSLOT + ldoff;
      RETRY3(dO0, dO1, dO2, hpr, expect);
      STRIP3(dO0, dO1, dO2);
    }
    BARRIER_LGKM;
    {
      f32x4 acc = {}, acc2 = {};
      if (j > 0) MFMA12(bfragB);
      PREW(x10, x11, x12, x13);
    }
    __builtin_amdgcn_sched_barrier(0);
    if (j >= 1) HLOAD3(dO0, dO1, dO2, hb3 + (size_t)ps * HSLOT + ldoff);      // h(ch3, j-1)
    if (j + 1 < NW) XG_ISSUE(x00, x01, x02, x03, xg_f, 0, j + 1);             // ch0 xg, tn=j+1
    BARRIER_LGKM;
    EW_STORE(c1, hb1, ta1, 0, hcOff1);

    //========== tick Y2: (d0, X1) ==========
    if (j == 0)            { asm volatile("s_waitcnt vmcnt(12)" ::: "memory"); }
    else if (j == NW - 1)  { asm volatile("s_waitcnt vmcnt(0)"  ::: "memory"); }
    else                   { asm volatile("s_waitcnt vmcnt(15)" ::: "memory"); }
    __builtin_amdgcn_sched_barrier(0);
    if (j > 0){
      const unsigned int* hpr = hb2 + (size_t)ps * HSLOT + ldoff;
      RETRY3(dE0, dE1, dE2, hpr, expect);
      STRIP3(dE0, dE1, dE2);
    }
    BARRIER_LGKM;
    {
      f32x4 acc = {}, acc2 = {};
      if (j > 0) MFMA12(bfragF);
      PREW(x20, x21, x22, x23);
    }
    __builtin_amdgcn_sched_barrier(0);
    if (j + 1 < NW) HLOAD3(dE0, dE1, dE2, hb0 + (size_t)(j & 1) * HSLOT + ldoff);  // h(ch0, j)
    if (j + 1 < NW) XG_ISSUE(x10, x11, x12, x13, xg_b, 0, NW - 2 - j);             // ch1 xg, tn=j+1
    BARRIER_LGKM;
    EW_STORE(c2, hb2, ta0, 16, hcOff0);

    //========== tick Y3: (d1, X1) ==========
    if (j == 0)            { asm volatile("s_waitcnt vmcnt(17)" ::: "memory"); }
    else if (j == NW - 1)  { asm volatile("s_waitcnt vmcnt(0)"  ::: "memory"); }
    else                   { asm volatile("s_waitcnt vmcnt(15)" ::: "memory"); }
    __builtin_amdgcn_sched_barrier(0);
    if (j > 0){
      const unsigned int* hpr = hb3 + (size_t)ps * HSLOT + ldoff;
      RETRY3(dO0, dO1, dO2, hpr, expect);
      STRIP3(dO0, dO1, dO2);
    }
    BARRIER_LGKM;
    {
      f32x4 acc = {}, acc2 = {};
      if (j > 0) MFMA12(bfragB);
      PREW(x30, x31, x32, x33);
    }
    __builtin_amdgcn_sched_barrier(0);
    if (j + 1 < NW) HLOAD3(dO0, dO1, dO2, hb1 + (size_t)(j & 1) * HSLOT + ldoff);  // h(ch1, j)
    if (j + 1 < NW) XG_ISSUE(x20, x21, x22, x23, xg_f, 1, j + 1);                  // ch2 xg, tn=j+1
    BARRIER_LGKM;
    EW_STORE(c3, hb3, ta1, 16, hcOff1);
  }
}

// ---------------- gate MLP + softmax (per batch row) ----------------
__global__ __launch_bounds__(256) void k_gate(const float* __restrict__ tok,
                                              const int* __restrict__ lids,
                                              const float* __restrict__ ltab,
                                              const float* __restrict__ W1,
                                              const float* __restrict__ b1v,
                                              const float* __restrict__ W2,
                                              const float* __restrict__ b2v,
                                              float* __restrict__ gate){
  __shared__ float gin[GIN];
  __shared__ float hid[HH];
  __shared__ float pr[EE];
  int b = blockIdx.x, tid = threadIdx.x;
  int lid = lids[b];
  for (int i = tid; i < GIN; i += 256)
    gin[i] = (i < HH) ? tok[(size_t)b * LL * HH + i] : ltab[lid * DLL + (i - HH)];
  __syncthreads();
  for (int j = tid; j < HH; j += 256){
    float a = b1v[j];
    const float* wr = W1 + (size_t)j * GIN;
    for (int k = 0; k < GIN; ++k) a += gin[k] * wr[k];
    hid[j] = fmaxf(a, 0.f);
  }
  __syncthreads();
  int wv = tid >> 6, lane = tid & 63;
  if (wv < EE){
    float p = 0.f;
    for (int k = lane; k < HH; k += 64) p += hid[k] * W2[wv * HH + k];
#pragma unroll
    for (int off = 32; off; off >>= 1) p += __shfl_down(p, off);
    if (lane == 0) pr[wv] = p + b2v[wv];
  }
  __syncthreads();
  if (tid == 0){
    float mx = fmaxf(fmaxf(pr[0], pr[1]), fmaxf(pr[2], pr[3]));
    float s = 0.f, ex[EE];
    for (int e2 = 0; e2 < EE; ++e2){ ex[e2] = __expf(pr[e2] - mx); s += ex[e2]; }
    for (int e2 = 0; e2 < EE; ++e2) gate[b * EE + e2] = ex[e2] / s;
  }
}

// ---------------- head precompute: A = headW @ proj_W, c = headW.proj_b + head_b ----------------
__global__ __launch_bounds__(256) void k_headpre(const float* __restrict__ efW,
                                                 const float* __restrict__ efb,
                                                 const float* __restrict__ edW,
                                                 const float* __restrict__ edb,
                                                 const float* __restrict__ projW,
                                                 const float* __restrict__ projb,
                                                 float* __restrict__ Acomb,
                                                 float* __restrict__ Ccomb){
  int head = blockIdx.x >> 2, e2 = blockIdx.x & 3, tid = threadIdx.x;
  const float* Wv = head ? edW : efW;
  const float* bv = head ? edb : efb;
  __shared__ float wrow[HH];
  for (int i = tid; i < HH; i += 256) wrow[i] = Wv[e2 * HH + i];
  __syncthreads();
  for (int c = tid; c < HH; c += 256){
    float a = 0.f;
    for (int h2 = 0; h2 < HH; ++h2) a += wrow[h2] * projW[(size_t)h2 * HH + c];
    Acomb[(head * 4 + e2) * HH + c] = a;
  }
  int wv = tid >> 6, lane = tid & 63;
  if (wv == 0){
    float p = 0.f;
    for (int k = lane; k < HH; k += 64) p += wrow[k] * projb[k];
#pragma unroll
    for (int off = 32; off; off >>= 1) p += __shfl_down(p, off);
    if (lane == 0) Ccomb[head * 4 + e2] = p + bv[e2];
  }
}

// ---------------- fused expert heads: out = sum_e gate * (hcat.A_e + c_e) ----------------
__global__ __launch_bounds__(256) void k_heads(const short* __restrict__ hcat,
                                               const float* __restrict__ Acomb,
                                               const float* __restrict__ Ccomb,
                                               const float* __restrict__ gate,
                                               float* __restrict__ outp){
  __shared__ float Al[8 * HH];   // 24 KB
  int tid = threadIdx.x;
  for (int i = tid; i < 8 * HH; i += 256) Al[i] = Acomb[i];
  __syncthreads();
  int wv = tid >> 6, lane = tid & 63;
  int bw = blockIdx.x * 4 + wv;        // = b*512 + w
  const short* hr = hcat + (size_t)bw * HH;
  float hv[12];
#pragma unroll
  for (int j = 0; j < 12; ++j) hv[j] = bf2f(hr[lane + 64 * j]);
  float dsum[8];
#pragma unroll
  for (int v = 0; v < 8; ++v){
    float p = 0.f;
#pragma unroll
    for (int j = 0; j < 12; ++j) p += hv[j] * Al[v * HH + lane + 64 * j];
#pragma unroll
    for (int off = 32; off; off >>= 1) p += __shfl_xor(p, off);
    dsum[v] = p;
  }
  if (lane == 0){
    int b = bw >> 9;
    float fx = 0.f, du = 0.f;
#pragma unroll
    for (int e2 = 0; e2 < 4; ++e2){
      float g = gate[b * 4 + e2];
      fx += g * (dsum[e2]     + Ccomb[e2]);
      du += g * (dsum[4 + e2] + Ccomb[4 + e2]);
    }
    outp[bw] = fx;
    outp[BB * NW + bw] = du;
  }
}

extern "C" void kernel_launch(void* const* d_in, const int* in_sizes, int n_in,
                              void* d_out, int out_size, void* d_ws, size_t ws_size,
                              hipStream_t stream){
  const float* tok   = (const float*)d_in[0];
  const int*   wmap  = (const int*)d_in[1];
  const int*   lids  = (const int*)d_in[2];
  const float* Wih_f = (const float*)d_in[3];
  const float* Whh_f = (const float*)d_in[4];
  const float* bih_f = (const float*)d_in[5];
  const float* bhh_f = (const float*)d_in[6];
  const float* Wih_b = (const float*)d_in[7];
  const float* Whh_b = (const float*)d_in[8];
  const float* bih_b = (const float*)d_in[9];
  const float* bhh_b = (const float*)d_in[10];
  const float* projW = (const float*)d_in[11];
  const float* projb = (const float*)d_in[12];
  const float* ltab  = (const float*)d_in[13];
  const float* gW1   = (const float*)d_in[14];
  const float* gb1   = (const float*)d_in[15];
  const float* gW2   = (const float*)d_in[16];
  const float* gb2   = (const float*)d_in[17];
  const float* efW   = (const float*)d_in[18];
  const float* efb   = (const float*)d_in[19];
  const float* edW   = (const float*)d_in[20];
  const float* edb   = (const float*)d_in[21];
  float* outp = (float*)d_out;

  char* ws = (char*)d_ws;
  size_t off = 0;
  auto alloc = [&](size_t bytes) -> char* {
    char* p = ws + off;
    off = (off + bytes + 255) & ~(size_t)255;
    return p;
  };
  short* we_bf   = (short*)alloc((size_t)BB * NW * HH * 2);
  short* wihf_bf = (short*)alloc((size_t)G4 * HH * 2);
  short* wihb_bf = (short*)alloc((size_t)G4 * HH * 2);
  short* whhf_bf = (short*)alloc((size_t)G4 * HID * 2);
  short* whhb_bf = (short*)alloc((size_t)G4 * HID * 2);
  float* xg_f    = (float*)alloc((size_t)BB * NW * G4 * 4);
  float* xg_b    = (float*)alloc((size_t)BB * NW * G4 * 4);
  short* hcat    = (short*)alloc((size_t)BB * NW * HH * 2);
  unsigned int* hbuf = (unsigned int*)alloc((size_t)4 * 2 * HSLOT * 4);  // 4 chains x 2 slots, tagged
  float* gateb   = (float*)alloc((size_t)BB * EE * 4);
  float* Acomb   = (float*)alloc((size_t)8 * HH * 4);
  float* Ccomb   = (float*)alloc((size_t)8 * 4);

  k_f2bf<<<1024, 256, 0, stream>>>(Wih_f, wihf_bf, G4 * HH);
  k_f2bf<<<1024, 256, 0, stream>>>(Wih_b, wihb_bf, G4 * HH);
  k_f2bf<<<512, 256, 0, stream>>>(Whh_f, whhf_bf, G4 * HID);
  k_f2bf<<<512, 256, 0, stream>>>(Whh_b, whhb_bf, G4 * HID);
  k_segmean<<<BB * NW, 256, 0, stream>>>(tok, wmap, we_bf);
  k_gemm_bt<<<(BB * NW / 128) * (G4 / 128), 256, 0, stream>>>(we_bf, wihf_bf, bih_f, bhh_f, xg_f, BB * NW, G4, HH);
  k_gemm_bt<<<(BB * NW / 128) * (G4 / 128), 256, 0, stream>>>(we_bf, wihb_bf, bih_b, bhh_b, xg_b, BB * NW, G4, HH);
  k_gate<<<BB, 256, 0, stream>>>(tok, lids, ltab, gW1, gb1, gW2, gb2, gateb);
  k_headpre<<<8, 256, 0, stream>>>(efW, efb, edW, edb, projW, projb, Acomb, Ccomb);
  k_lstm<<<CWG, 512, 0, stream>>>(xg_f, xg_b, whhf_bf, whhb_bf, hbuf, hcat);
  k_heads<<<(BB * NW) / 4, 256, 0, stream>>>(hcat, Acomb, Ccomb, gateb, outp);
}

// Round 12
// 3664.470 us; speedup vs baseline: 1.0017x; 1.0017x over previous
//
#include <hip/hip_runtime.h>
#include <stdint.h>

#define BB 32
#define LL 1024
#define NW 512
#define HH 768
#define HID 384
#define G4 1536   // 4*HID
#define EE 4
#define DLL 128
#define GIN 896   // H+DL
#define CWG 12    // column-group WGs (each handles BOTH dirs, 32 cols)
#define WGC 32    // h-cols per WG
#define HPAD 392  // padded LDS row stride (shorts)
#define HSLOT (16 * HID)   // one tagged h slot (u32 count)

typedef __attribute__((ext_vector_type(8))) short short8;
typedef __attribute__((ext_vector_type(4))) float f32x4;
typedef __attribute__((ext_vector_type(4))) unsigned int u32x4;
typedef __attribute__((ext_vector_type(2))) unsigned int u32x2;

__device__ __forceinline__ float bf2f(short s){
  union { unsigned int u; float f; } v; v.u = ((unsigned int)(unsigned short)s) << 16; return v.f;
}
__device__ __forceinline__ short f2bf(float f){
  union { float f; unsigned int u; } v; v.f = f;
  unsigned int r = v.u + 0x7fffu + ((v.u >> 16) & 1u);
  return (short)(r >> 16);
}
__device__ __forceinline__ float sigm(float x){ return 1.f / (1.f + __expf(-x)); }
__device__ __forceinline__ float ftanh(float x){ float e = __expf(2.f * x); return 1.f - 2.f / (e + 1.f); }

__device__ __forceinline__ void gload16(const void* g, void* l){
  __builtin_amdgcn_global_load_lds(
      (const __attribute__((address_space(1))) unsigned int*)g,
      (__attribute__((address_space(3))) unsigned int*)l, 16, 0, 0);
}

// ---------------- f32 -> bf16 convert ----------------
__global__ void k_f2bf(const float* in, short* out, int n){
  int i = blockIdx.x * blockDim.x + threadIdx.x;
  int st = gridDim.x * blockDim.x;
  for (; i < n; i += st) out[i] = f2bf(in[i]);
}

// ---------------- segment mean pooling ----------------
__global__ __launch_bounds__(256) void k_segmean(const float* __restrict__ tok,
                                                 const int* __restrict__ wmap,
                                                 short* __restrict__ we_bf){
  int blk = blockIdx.x;
  int b = blk >> 9;
  int w = blk & 511;
  const int* m = wmap + b * LL;
  int lo = 0, hi = LL;
  while (lo < hi){ int mid = (lo + hi) >> 1; if (m[mid] < w) lo = mid + 1; else hi = mid; }
  int s = lo;
  int lo2 = s, hi2 = LL;
  while (lo2 < hi2){ int mid = (lo2 + hi2) >> 1; if (m[mid] <= w) lo2 = mid + 1; else hi2 = mid; }
  int e = lo2;
  float cnt = (float)(e - s);
  float denom = fmaxf(cnt, 1.f);
  for (int j = threadIdx.x; j < HH; j += 256){
    float acc = 0.f;
    for (int r = s; r < e; ++r) acc += tok[((size_t)b * LL + r) * HH + j];
    we_bf[((size_t)b * NW + w) * HH + j] = f2bf(acc / denom);
  }
}

// ---------------- GEMM: C[M,N] = A[M,K](bf16) * W[N,K]^T(bf16) + b1[n] + b2[n] ----------------
__global__ __launch_bounds__(256) void k_gemm_bt(const short* __restrict__ Abf,
                                                 const short* __restrict__ Wbf,
                                                 const float* __restrict__ b1,
                                                 const float* __restrict__ b2,
                                                 float* __restrict__ Cf,
                                                 int M, int N, int K){
  __shared__ __attribute__((aligned(16))) short As[128 * 32];
  __shared__ __attribute__((aligned(16))) short Bs[128 * 32];
  int ntiles = N >> 7;
  int m0 = (blockIdx.x / ntiles) << 7;
  int n0 = (blockIdx.x % ntiles) << 7;
  int tid = threadIdx.x, lane = tid & 63, wv = tid >> 6;
  int wm = (wv >> 1) << 6, wn = (wv & 1) << 6;
  f32x4 acc[4][4] = {};
  for (int kk = 0; kk < K; kk += 32){
#pragma unroll
    for (int q = 0; q < 2; ++q){
      int e = q * 256 + tid;
      int row = e >> 2, col = (e & 3) << 3;
      gload16(Abf + (size_t)(m0 + row) * K + kk + col, As + e * 8);
      gload16(Wbf + (size_t)(n0 + row) * K + kk + col, Bs + e * 8);
    }
    __syncthreads();
    short8 af[4], bfr[4];
#pragma unroll
    for (int x = 0; x < 4; ++x){
      af[x]  = *(const short8*)(As + (wm + x * 16 + (lane & 15)) * 32 + ((lane >> 4) << 3));
      bfr[x] = *(const short8*)(Bs + (wn + x * 16 + (lane & 15)) * 32 + ((lane >> 4) << 3));
    }
#pragma unroll
    for (int x = 0; x < 4; ++x)
#pragma unroll
      for (int y = 0; y < 4; ++y)
        acc[x][y] = __builtin_amdgcn_mfma_f32_16x16x32_bf16(af[x], bfr[y], acc[x][y], 0, 0, 0);
    __syncthreads();
  }
#pragma unroll
  for (int x = 0; x < 4; ++x)
#pragma unroll
    for (int y = 0; y < 4; ++y)
#pragma unroll
      for (int i = 0; i < 4; ++i){
        int mm = m0 + wm + x * 16 + ((lane >> 4) << 2) + i;
        int nn = n0 + wn + y * 16 + (lane & 15);
        Cf[(size_t)mm * N + nn] = acc[x][y][i] + b1[nn] + b2[nn];
      }
}

// ================= BiLSTM: 4-chain rotation (dir x batch-half), tags, counted vmcnt =================
// 12 WGs x 512 threads; each WG owns 32 cols of BOTH directions and cycles 4 independent chains:
// Y0=(d0,X0) Y1=(d1,X0) Y2=(d0,X1) Y3=(d1,X1). h(C,t): u32=(bf16<<16)|(t+1) in hbuf[C][t&1].
// Schedule per tick: head vmcnt(15) [steady] -> tag-check (retry=rare) -> strip->LDS -> barrier ->
// MFMA -> pre -> mid{h-load for tick+2, xg for tick+3} -> barrier -> cell -> {tagged store, hcat store}.
// Store->load-issue = 1.5 ticks (covers MALL propagation); load flight = 1.5 ticks (covers RT).
// Safety: all-column tag validation at each head is the back-pressure (a producer cannot overwrite
// slot s before every WG validated the previous tag in s). Tags make any vmcnt slack self-healing.

#define TB(dv, EXP) (((dv[0] ^ (EXP)) | (dv[1] ^ (EXP)) | (dv[2] ^ (EXP)) | (dv[3] ^ (EXP))) & 0xffffu)

#define HLOAD3(D0, D1, D2, PTR) do{ const unsigned int* _hp = (PTR); \
  asm volatile("global_load_dwordx4 %0, %1, off sc0 sc1" : "=v"(D0) : "v"(_hp + 0) : "memory"); \
  asm volatile("global_load_dwordx4 %0, %1, off sc0 sc1" : "=v"(D1) : "v"(_hp + 4) : "memory"); \
  asm volatile("global_load_dwordx4 %0, %1, off sc0 sc1" : "=v"(D2) : "v"(_hp + 8) : "memory"); }while(0)

#define RETRY3(D0, D1, D2, PTR, EXP) for(;;){ \
  unsigned int _bad = TB(D0, EXP) | TB(D1, EXP) | TB(D2, EXP); \
  if (__all(_bad == 0)) break; \
  __builtin_amdgcn_s_sleep(1); \
  HLOAD3(D0, D1, D2, PTR); \
  asm volatile("s_waitcnt vmcnt(0)" ::: "memory"); \
  __builtin_amdgcn_sched_barrier(0); }

#define STRIP3(D0, D1, D2) do{ \
  unsigned int _p0 = (D0[0] >> 16) | (D0[1] & 0xffff0000u); \
  unsigned int _p1 = (D0[2] >> 16) | (D0[3] & 0xffff0000u); \
  unsigned int _p2 = (D1[0] >> 16) | (D1[1] & 0xffff0000u); \
  unsigned int _p3 = (D1[2] >> 16) | (D1[3] & 0xffff0000u); \
  unsigned int _p4 = (D2[0] >> 16) | (D2[1] & 0xffff0000u); \
  unsigned int _p5 = (D2[2] >> 16) | (D2[3] & 0xffff0000u); \
  u32x2 _w0 = {_p0, _p1}, _w1 = {_p2, _p3}, _w2 = {_p4, _p5}; \
  short* _dst = &hs[eb * HPAD + scc]; \
  *(u32x2*)(_dst)     = _w0; \
  *(u32x2*)(_dst + 4) = _w1; \
  *(u32x2*)(_dst + 8) = _w2; }while(0)

#define XG_ISSUE(A0, A1, A2, A3, BASE, XHV, TACT) do{ \
  const float* _xp = (BASE) + ((size_t)((XHV) * 16 + q * 4) * NW + (TACT)) * G4 + colOff; \
  asm volatile("global_load_dword %0, %1, off" : "=v"(A0) : "v"(_xp) : "memory"); \
  asm volatile("global_load_dword %0, %1, off" : "=v"(A1) : "v"(_xp + (size_t)NW * G4) : "memory"); \
  asm volatile("global_load_dword %0, %1, off" : "=v"(A2) : "v"(_xp + (size_t)2 * NW * G4) : "memory"); \
  asm volatile("global_load_dword %0, %1, off" : "=v"(A3) : "v"(_xp + (size_t)3 * NW * G4) : "memory"); }while(0)

#define BARRIER_LGKM \
  asm volatile("s_waitcnt lgkmcnt(0)" ::: "memory"); \
  __builtin_amdgcn_s_barrier(); \
  __builtin_amdgcn_sched_barrier(0);

#define MFMA12(BF) { const short* _hr = &hs[fr * HPAD + q * 8]; \
  _Pragma("unroll") \
  for (int ks = 0; ks < 6; ++ks) \
    acc  = __builtin_amdgcn_mfma_f32_16x16x32_bf16(*(const short8*)(_hr + ks * 32), BF[ks], acc, 0, 0, 0); \
  _Pragma("unroll") \
  for (int ks = 6; ks < 12; ++ks) \
    acc2 = __builtin_amdgcn_mfma_f32_16x16x32_bf16(*(const short8*)(_hr + ks * 32), BF[ks], acc2, 0, 0, 0); \
  acc += acc2; }

#define PREW(A0, A1, A2, A3) \
  pre[g][q*4+0][nh*16+fr] = acc[0] + (A0); \
  pre[g][q*4+1][nh*16+fr] = acc[1] + (A1); \
  pre[g][q*4+2][nh*16+fr] = acc[2] + (A2); \
  pre[g][q*4+3][nh*16+fr] = acc[3] + (A3);

#define EW_STORE(CST, HBC, TACT, ROWBASE, HCOFF) do{ \
  float _gi = pre[0][eb][ecol], _gf = pre[1][eb][ecol]; \
  float _gg = pre[2][eb][ecol], _go = pre[3][eb][ecol]; \
  CST = sigm(_gf) * CST + sigm(_gi) * ftanh(_gg); \
  float _h = sigm(_go) * ftanh(CST); \
  unsigned int _hv = (unsigned int)(unsigned short)f2bf(_h); \
  unsigned int _wt = (_hv << 16) | ((unsigned int)(j + 1) & 0xffffu); \
  unsigned int* _hw = (HBC) + (size_t)(j & 1) * HSLOT + stoff; \
  asm volatile("global_store_dword %0, %1, off sc0 sc1" :: "v"(_hw), "v"(_wt) : "memory"); \
  short* _hc = hcat + ((size_t)((ROWBASE) + eb) * NW + (TACT)) * HH + (HCOFF); \
  asm volatile("global_store_short %0, %1, off" :: "v"(_hc), "v"(_hv) : "memory"); }while(0)

__global__ __launch_bounds__(512) void k_lstm(const float* __restrict__ xg_f,
                                              const float* __restrict__ xg_b,
                                              const short* __restrict__ whh_f,
                                              const short* __restrict__ whh_b,
                                              unsigned int* __restrict__ hbuf,
                                              short* __restrict__ hcat){
  int cg = blockIdx.x;
  int tid = threadIdx.x, lane = tid & 63, wv = tid >> 6;
  int q = lane >> 4, fr = lane & 15;
  int g = wv >> 1, nh = wv & 1;
  int jbase = g * HID + cg * WGC + nh * 16;
  int colOff = jbase + fr;

  // resident Whh fragments for BOTH directions: 2 x 48 VGPRs
  short8 bfragF[12], bfragB[12];
  {
    const short* wrF = whh_f + (size_t)(jbase + fr) * HID + q * 8;
    const short* wrB = whh_b + (size_t)(jbase + fr) * HID + q * 8;
#pragma unroll
    for (int ks = 0; ks < 12; ++ks)
      asm volatile("global_load_dwordx4 %0, %1, off" : "=v"(bfragF[ks]) : "v"(wrF + ks * 32) : "memory");
#pragma unroll
    for (int ks = 0; ks < 12; ++ks)
      asm volatile("global_load_dwordx4 %0, %1, off" : "=v"(bfragB[ks]) : "v"(wrB + ks * 32) : "memory");
    asm volatile("s_waitcnt vmcnt(0)" ::: "memory");
    __builtin_amdgcn_sched_barrier(0);
  }

  __shared__ __attribute__((aligned(16))) short hs[16 * HPAD];
  __shared__ float pre[4][16][34];

  int eb = tid >> 5, ecol = tid & 31;
  int scc = ecol * 12;                       // staging: 12 consecutive cells
  int ldoff = eb * HID + scc;
  int stoff = eb * HID + cg * WGC + ecol;
  int hcOff0 = cg * WGC + ecol;              // dir0 hcat col
  int hcOff1 = HID + cg * WGC + ecol;        // dir1 hcat col
  unsigned int* hb0 = hbuf;                  // chain (d0,X0)
  unsigned int* hb1 = hbuf + 2 * HSLOT;      // (d1,X0)
  unsigned int* hb2 = hbuf + 4 * HSLOT;      // (d0,X1)
  unsigned int* hb3 = hbuf + 6 * HSLOT;      // (d1,X1)

  float c0 = 0.f, c1 = 0.f, c2 = 0.f, c3 = 0.f;
  float x00, x01, x02, x03, x10, x11, x12, x13;
  float x20, x21, x22, x23, x30, x31, x32, x33;
  u32x4 dE0 = {}, dE1 = {}, dE2 = {}, dO0 = {}, dO1 = {}, dO2 = {};

  // prologue xg: ticks 0,1,2 (chains 0,1,2 at t=0)
  XG_ISSUE(x00, x01, x02, x03, xg_f, 0, 0);
  XG_ISSUE(x10, x11, x12, x13, xg_b, 0, NW - 1);
  XG_ISSUE(x20, x21, x22, x23, xg_f, 1, 0);

  for (int j = 0; j < NW; ++j){
    int ta0 = j;               // dir0 time index
    int ta1 = NW - 1 - j;      // dir1 time index
    int ps = (j - 1) & 1;      // slot holding h(.., j-1)
    unsigned int expect = (unsigned int)j & 0xffffu;

    //========== tick Y0: (d0, X0) ==========
    if (j == 0)            { asm volatile("s_waitcnt vmcnt(8)"  ::: "memory"); }
    else if (j == NW - 1)  { asm volatile("s_waitcnt vmcnt(0)"  ::: "memory"); }
    else                   { asm volatile("s_waitcnt vmcnt(15)" ::: "memory"); }
    __builtin_amdgcn_sched_barrier(0);
    if (j > 0){
      const unsigned int* hpr = hb0 + (size_t)ps * HSLOT + ldoff;
      RETRY3(dE0, dE1, dE2, hpr, expect);
      STRIP3(dE0, dE1, dE2);
    }
    BARRIER_LGKM;
    {
      f32x4 acc = {}, acc2 = {};
      if (j > 0) MFMA12(bfragF);
      PREW(x00, x01, x02, x03);
    }
    __builtin_amdgcn_sched_barrier(0);
    if (j >= 1) HLOAD3(dE0, dE1, dE2, hb2 + (size_t)ps * HSLOT + ldoff);      // h(ch2, j-1) for tick+2
    XG_ISSUE(x30, x31, x32, x33, xg_b, 1, ta1);                                // ch3 xg, tn=j
    BARRIER_LGKM;
    EW_STORE(c0, hb0, ta0, 0, hcOff0);

    //========== tick Y1: (d1, X0) ==========
    if (j == 0)            { asm volatile("s_waitcnt vmcnt(10)" ::: "memory"); }
    else if (j == NW - 1)  { asm volatile("s_waitcnt vmcnt(0)"  ::: "memory"); }
    else                   { asm volatile("s_waitcnt vmcnt(15)" ::: "memory"); }
    __builtin_amdgcn_sched_barrier(0);
    if (j > 0){
      const unsigned int* hpr = hb1 + (size_t)ps * HSLOT + ldoff;
      RETRY3(dO0, dO1, dO2, hpr, expect);
      STRIP3(dO0, dO1, dO2);
    }
    BARRIER_LGKM;
    {
      f32x4 acc = {}, acc2 = {};
      if (j > 0) MFMA12(bfragB);
      PREW(x10, x11, x12, x13);
    }
    __builtin_amdgcn_sched_barrier(0);
    if (j >= 1) HLOAD3(dO0, dO1, dO2, hb3 + (size_t)ps * HSLOT + ldoff);      // h(ch3, j-1)
    if (j + 1 < NW) XG_ISSUE(x00, x01, x02, x03, xg_f, 0, j + 1);             // ch0 xg, tn=j+1
    BARRIER_LGKM;
    EW_STORE(c1, hb1, ta1, 0, hcOff1);

    //========== tick Y2: (d0, X1) ==========
    if (j == 0)            { asm volatile("s_waitcnt vmcnt(12)" ::: "memory"); }
    else if (j == NW - 1)  { asm volatile("s_waitcnt vmcnt(0)"  ::: "memory"); }
    else                   { asm volatile("s_waitcnt vmcnt(15)" ::: "memory"); }
    __builtin_amdgcn_sched_barrier(0);
    if (j > 0){
      const unsigned int* hpr = hb2 + (size_t)ps * HSLOT + ldoff;
      RETRY3(dE0, dE1, dE2, hpr, expect);
      STRIP3(dE0, dE1, dE2);
    }
    BARRIER_LGKM;
    {
      f32x4 acc = {}, acc2 = {};
      if (j > 0) MFMA12(bfragF);
      PREW(x20, x21, x22, x23);
    }
    __builtin_amdgcn_sched_barrier(0);
    if (j + 1 < NW) HLOAD3(dE0, dE1, dE2, hb0 + (size_t)(j & 1) * HSLOT + ldoff);  // h(ch0, j)
    if (j + 1 < NW) XG_ISSUE(x10, x11, x12, x13, xg_b, 0, NW - 2 - j);             // ch1 xg, tn=j+1
    BARRIER_LGKM;
    EW_STORE(c2, hb2, ta0, 16, hcOff0);

    //========== tick Y3: (d1, X1) ==========
    if (j == 0)            { asm volatile("s_waitcnt vmcnt(17)" ::: "memory"); }
    else if (j == NW - 1)  { asm volatile("s_waitcnt vmcnt(0)"  ::: "memory"); }
    else                   { asm volatile("s_waitcnt vmcnt(15)" ::: "memory"); }
    __builtin_amdgcn_sched_barrier(0);
    if (j > 0){
      const unsigned int* hpr = hb3 + (size_t)ps * HSLOT + ldoff;
      RETRY3(dO0, dO1, dO2, hpr, expect);
      STRIP3(dO0, dO1, dO2);
    }
    BARRIER_LGKM;
    {
      f32x4 acc = {}, acc2 = {};
      if (j > 0) MFMA12(bfragB);
      PREW(x30, x31, x32, x33);
    }
    __builtin_amdgcn_sched_barrier(0);
    if (j + 1 < NW) HLOAD3(dO0, dO1, dO2, hb1 + (size_t)(j & 1) * HSLOT + ldoff);  // h(ch1, j)
    if (j + 1 < NW) XG_ISSUE(x20, x21, x22, x23, xg_f, 1, j + 1);                  // ch2 xg, tn=j+1
    BARRIER_LGKM;
    EW_STORE(c3, hb3, ta1, 16, hcOff1);
  }
}

// ---------------- gate MLP + softmax (per batch row) ----------------
__global__ __launch_bounds__(256) void k_gate(const float* __restrict__ tok,
                                              const int* __restrict__ lids,
                                              const float* __restrict__ ltab,
                                              const float* __restrict__ W1,
                                              const float* __restrict__ b1v,
                                              const float* __restrict__ W2,
                                              const float* __restrict__ b2v,
                                              float* __restrict__ gate){
  __shared__ float gin[GIN];
  __shared__ float hid[HH];
  __shared__ float pr[EE];
  int b = blockIdx.x, tid = threadIdx.x;
  int lid = lids[b];
  for (int i = tid; i < GIN; i += 256)
    gin[i] = (i < HH) ? tok[(size_t)b * LL * HH + i] : ltab[lid * DLL + (i - HH)];
  __syncthreads();
  for (int j = tid; j < HH; j += 256){
    float a = b1v[j];
    const float* wr = W1 + (size_t)j * GIN;
    for (int k = 0; k < GIN; ++k) a += gin[k] * wr[k];
    hid[j] = fmaxf(a, 0.f);
  }
  __syncthreads();
  int wv = tid >> 6, lane = tid & 63;
  if (wv < EE){
    float p = 0.f;
    for (int k = lane; k < HH; k += 64) p += hid[k] * W2[wv * HH + k];
#pragma unroll
    for (int off = 32; off; off >>= 1) p += __shfl_down(p, off);
    if (lane == 0) pr[wv] = p + b2v[wv];
  }
  __syncthreads();
  if (tid == 0){
    float mx = fmaxf(fmaxf(pr[0], pr[1]), fmaxf(pr[2], pr[3]));
    float s = 0.f, ex[EE];
    for (int e2 = 0; e2 < EE; ++e2){ ex[e2] = __expf(pr[e2] - mx); s += ex[e2]; }
    for (int e2 = 0; e2 < EE; ++e2) gate[b * EE + e2] = ex[e2] / s;
  }
}

// ---------------- head precompute: A = headW @ proj_W, c = headW.proj_b + head_b ----------------
__global__ __launch_bounds__(256) void k_headpre(const float* __restrict__ efW,
                                                 const float* __restrict__ efb,
                                                 const float* __restrict__ edW,
                                                 const float* __restrict__ edb,
                                                 const float* __restrict__ projW,
                                                 const float* __restrict__ projb,
                                                 float* __restrict__ Acomb,
                                                 float* __restrict__ Ccomb){
  int head = blockIdx.x >> 2, e2 = blockIdx.x & 3, tid = threadIdx.x;
  const float* Wv = head ? edW : efW;
  const float* bv = head ? edb : efb;
  __shared__ float wrow[HH];
  for (int i = tid; i < HH; i += 256) wrow[i] = Wv[e2 * HH + i];
  __syncthreads();
  for (int c = tid; c < HH; c += 256){
    float a = 0.f;
    for (int h2 = 0; h2 < HH; ++h2) a += wrow[h2] * projW[(size_t)h2 * HH + c];
    Acomb[(head * 4 + e2) * HH + c] = a;
  }
  int wv = tid >> 6, lane = tid & 63;
  if (wv == 0){
    float p = 0.f;
    for (int k = lane; k < HH; k += 64) p += wrow[k] * projb[k];
#pragma unroll
    for (int off = 32; off; off >>= 1) p += __shfl_down(p, off);
    if (lane == 0) Ccomb[head * 4 + e2] = p + bv[e2];
  }
}

// ---------------- fused expert heads: out = sum_e gate * (hcat.A_e + c_e) ----------------
__global__ __launch_bounds__(256) void k_heads(const short* __restrict__ hcat,
                                               const float* __restrict__ Acomb,
                                               const float* __restrict__ Ccomb,
                                               const float* __restrict__ gate,
                                               float* __restrict__ outp){
  __shared__ float Al[8 * HH];   // 24 KB
  int tid = threadIdx.x;
  for (int i = tid; i < 8 * HH; i += 256) Al[i] = Acomb[i];
  __syncthreads();
  int wv = tid >> 6, lane = tid & 63;
  int bw = blockIdx.x * 4 + wv;        // = b*512 + w
  const short* hr = hcat + (size_t)bw * HH;
  float hv[12];
#pragma unroll
  for (int j = 0; j < 12; ++j) hv[j] = bf2f(hr[lane + 64 * j]);
  float dsum[8];
#pragma unroll
  for (int v = 0; v < 8; ++v){
    float p = 0.f;
#pragma unroll
    for (int j = 0; j < 12; ++j) p += hv[j] * Al[v * HH + lane + 64 * j];
#pragma unroll
    for (int off = 32; off; off >>= 1) p += __shfl_xor(p, off);
    dsum[v] = p;
  }
  if (lane == 0){
    int b = bw >> 9;
    float fx = 0.f, du = 0.f;
#pragma unroll
    for (int e2 = 0; e2 < 4; ++e2){
      float g = gate[b * 4 + e2];
      fx += g * (dsum[e2]     + Ccomb[e2]);
      du += g * (dsum[4 + e2] + Ccomb[4 + e2]);
    }
    outp[bw] = fx;
    outp[BB * NW + bw] = du;
  }
}

extern "C" void kernel_launch(void* const* d_in, const int* in_sizes, int n_in,
                              void* d_out, int out_size, void* d_ws, size_t ws_size,
                              hipStream_t stream){
  const float* tok   = (const float*)d_in[0];
  const int*   wmap  = (const int*)d_in[1];
  const int*   lids  = (const int*)d_in[2];
  const float* Wih_f = (const float*)d_in[3];
  const float* Whh_f = (const float*)d_in[4];
  const float* bih_f = (const float*)d_in[5];
  const float* bhh_f = (const float*)d_in[6];
  const float* Wih_b = (const float*)d_in[7];
  const float* Whh_b = (const float*)d_in[8];
  const float* bih_b = (const float*)d_in[9];
  const float* bhh_b = (const float*)d_in[10];
  const float* projW = (const float*)d_in[11];
  const float* projb = (const float*)d_in[12];
  const float* ltab  = (const float*)d_in[13];
  const float* gW1   = (const float*)d_in[14];
  const float* gb1   = (const float*)d_in[15];
  const float* gW2   = (const float*)d_in[16];
  const float* gb2   = (const float*)d_in[17];
  const float* efW   = (const float*)d_in[18];
  const float* efb   = (const float*)d_in[19];
  const float* edW   = (const float*)d_in[20];
  const float* edb   = (const float*)d_in[21];
  float* outp = (float*)d_out;

  char* ws = (char*)d_ws;
  size_t off = 0;
  auto alloc = [&](size_t bytes) -> char* {
    char* p = ws + off;
    off = (off + bytes + 255) & ~(size_t)255;
    return p;
  };
  short* we_bf   = (short*)alloc((size_t)BB * NW * HH * 2);
  short* wihf_bf = (short*)alloc((size_t)G4 * HH * 2);
  short* wihb_bf = (short*)alloc((size_t)G4 * HH * 2);
  short* whhf_bf = (short*)alloc((size_t)G4 * HID * 2);
  short* whhb_bf = (short*)alloc((size_t)G4 * HID * 2);
  float* xg_f    = (float*)alloc((size_t)BB * NW * G4 * 4);
  float* xg_b    = (float*)alloc((size_t)BB * NW * G4 * 4);
  short* hcat    = (short*)alloc((size_t)BB * NW * HH * 2);
  unsigned int* hbuf = (unsigned int*)alloc((size_t)4 * 2 * HSLOT * 4);  // 4 chains x 2 slots, tagged
  float* gateb   = (float*)alloc((size_t)BB * EE * 4);
  float* Acomb   = (float*)alloc((size_t)8 * HH * 4);
  float* Ccomb   = (float*)alloc((size_t)8 * 4);

  k_f2bf<<<1024, 256, 0, stream>>>(Wih_f, wihf_bf, G4 * HH);
  k_f2bf<<<1024, 256, 0, stream>>>(Wih_b, wihb_bf, G4 * HH);
  k_f2bf<<<512, 256, 0, stream>>>(Whh_f, whhf_bf, G4 * HID);
  k_f2bf<<<512, 256, 0, stream>>>(Whh_b, whhb_bf, G4 * HID);
  k_segmean<<<BB * NW, 256, 0, stream>>>(tok, wmap, we_bf);
  k_gemm_bt<<<(BB * NW / 128) * (G4 / 128), 256, 0, stream>>>(we_bf, wihf_bf, bih_f, bhh_f, xg_f, BB * NW, G4, HH);
  k_gemm_bt<<<(BB * NW / 128) * (G4 / 128), 256, 0, stream>>>(we_bf, wihb_bf, bih_b, bhh_b, xg_b, BB * NW, G4, HH);
  k_gate<<<BB, 256, 0, stream>>>(tok, lids, ltab, gW1, gb1, gW2, gb2, gateb);
  k_headpre<<<8, 256, 0, stream>>>(efW, efb, edW, edb, projW, projb, Acomb, Ccomb);
  k_lstm<<<CWG, 512, 0, stream>>>(xg_f, xg_b, whhf_bf, whhb_bf, hbuf, hcat);
  k_heads<<<(BB * NW) / 4, 256, 0, stream>>>(hcat, Acomb, Ccomb, gateb, outp);
}